// Round 1
// baseline (766.880 us; speedup 1.0000x reference)
//
#include <hip/hip_runtime.h>
#include <math.h>

#define H_ 128
#define W_ 128
#define C_ 64
#define B_ 8
#define HW 16384          // H_*W_
#define NPIX (B_*HW)      // 131072

__device__ __forceinline__ float softplusf(float v) {
    return fmaxf(v, 0.f) + log1pf(expf(-fabsf(v)));
}

// K1: r = W_reduce @ x + b_reduce (per pixel); write r to rbuf; accumulate
// per-channel sum and sumsq for BatchNorm batch stats.
__global__ __launch_bounds__(256) void k1_r_stats(
    const float* __restrict__ x, const float* __restrict__ wr,
    const float* __restrict__ br, float* __restrict__ rbuf,
    float* __restrict__ stats /* sum[64], sumsq[64] */)
{
    __shared__ float wrs[C_ * C_];
    __shared__ float lsum[C_], lsq[C_];
    int tid = threadIdx.x;
    for (int i = tid; i < C_ * C_; i += 256) wrs[i] = wr[i];
    if (tid < C_) { lsum[tid] = 0.f; lsq[tid] = 0.f; }
    __syncthreads();

    int pid = blockIdx.x * 256 + tid;     // global pixel id
    int b   = pid >> 14;
    int rem = pid & (HW - 1);
    const float* xp = x + (((size_t)b * C_) << 14) + rem;

    float xv[C_];
#pragma unroll
    for (int c = 0; c < C_; ++c) xv[c] = xp[(size_t)c << 14];

    float* rp = rbuf + (((size_t)b * C_) << 14) + rem;
    int lane = tid & 63;

    for (int o = 0; o < C_; ++o) {
        float acc = br[o];
        const float4* wro = reinterpret_cast<const float4*>(&wrs[o * C_]);
#pragma unroll
        for (int c4 = 0; c4 < C_ / 4; ++c4) {
            float4 wv = wro[c4];
            acc += wv.x * xv[4*c4] + wv.y * xv[4*c4+1]
                 + wv.z * xv[4*c4+2] + wv.w * xv[4*c4+3];
        }
        rp[(size_t)o << 14] = acc;
        float s = acc, q = acc * acc;
#pragma unroll
        for (int m = 32; m; m >>= 1) {
            s += __shfl_xor(s, m, 64);
            q += __shfl_xor(q, m, 64);
        }
        if (lane == 0) { atomicAdd(&lsum[o], s); atomicAdd(&lsq[o], q); }
    }
    __syncthreads();
    if (tid < C_) {
        atomicAdd(&stats[tid], lsum[tid]);
        atomicAdd(&stats[C_ + tid], lsq[tid]);
    }
}

// K2: fold BN stats + gamma/beta into rn = relu(a*r + c)
__global__ void k2_finalize(const float* __restrict__ stats,
                            const float* __restrict__ gamma,
                            const float* __restrict__ beta,
                            float* __restrict__ ac /* a[64], c[64] */)
{
    int o = threadIdx.x;
    if (o < C_) {
        float inv_n = 1.f / (float)NPIX;
        float mu  = stats[o] * inv_n;
        float var = stats[C_ + o] * inv_n - mu * mu;
        float is  = rsqrtf(var + 1e-5f);
        float a   = gamma[o] * is;
        ac[o]      = a;
        ac[C_ + o] = beta[o] - mu * a;
    }
}

// K3: kern[9] per pixel from r; involution over 3x3 x-patches; softplus -> z
__global__ __launch_bounds__(256) void k3_involution(
    const float* __restrict__ x, const float* __restrict__ rbuf,
    const float* __restrict__ ac, const float* __restrict__ wspan,
    const float* __restrict__ bspan, float* __restrict__ z)
{
    __shared__ float wst[C_ * 12];       // transposed w_span, row pitch 12
    __shared__ float a_s[C_], c_s[C_];
    __shared__ float xt[2][18][19];
    int tid = threadIdx.x;
    for (int i = tid; i < 9 * C_; i += 256) {
        int k = i >> 6, o = i & 63;
        wst[o * 12 + k] = wspan[i];      // wspan[k*64+o]
    }
    if (tid < C_) { a_s[tid] = ac[tid]; c_s[tid] = ac[C_ + tid]; }

    int blk = blockIdx.x;
    int b = blk >> 6;
    int t = blk & 63;
    int h0 = (t >> 3) << 4;
    int w0 = (t & 7) << 4;
    int ty = tid >> 4, tx = tid & 15;
    int h = h0 + ty, w = w0 + tx;
    int pix = h * W_ + w;
    size_t base_b = ((size_t)b * C_) << 14;
    __syncthreads();

    float kern[9];
#pragma unroll
    for (int k = 0; k < 9; ++k) kern[k] = bspan[k];

    for (int o = 0; o < C_; ++o) {
        float rv = rbuf[base_b + ((size_t)o << 14) + pix];
        float rn = fmaxf(a_s[o] * rv + c_s[o], 0.f);
        const float* wo = &wst[o * 12];
#pragma unroll
        for (int k = 0; k < 9; ++k) kern[k] += wo[k] * rn;
    }

    for (int c = 0; c < C_; ++c) {
        int buf = c & 1;
        const float* xc = x + base_b + ((size_t)c << 14);
        for (int idx = tid; idx < 18 * 18; idx += 256) {
            int ly = idx / 18, lx = idx - ly * 18;
            int gh = h0 + ly - 1, gw = w0 + lx - 1;
            float v = 0.f;
            if (gh >= 0 && gh < H_ && gw >= 0 && gw < W_) v = xc[gh * W_ + gw];
            xt[buf][ly][lx] = v;
        }
        __syncthreads();
        float acc = 0.f;
#pragma unroll
        for (int i = 0; i < 3; ++i)
#pragma unroll
            for (int j = 0; j < 3; ++j)
                acc += kern[i * 3 + j] * xt[buf][ty + i][tx + j];
        z[base_b + ((size_t)c << 14) + pix] = softplusf(acc);
    }
}

// K4: dense 3x3 conv 64->64 + bias + softplus
__global__ __launch_bounds__(256) void k4_conv2(
    const float* __restrict__ z, const float* __restrict__ w2,
    const float* __restrict__ b2, float* __restrict__ out)
{
    __shared__ float zt[32][18][19];     // 43,776 B
    int tid = threadIdx.x;
    int blk = blockIdx.x;
    int b = blk >> 6;
    int t = blk & 63;
    int h0 = (t >> 3) << 4;
    int w0 = (t & 7) << 4;
    int ty = tid >> 4, tx = tid & 15;
    int h = h0 + ty, w = w0 + tx;
    size_t base_b = ((size_t)b * C_) << 14;

    float acc[C_];
#pragma unroll
    for (int o = 0; o < C_; ++o) acc[o] = b2[o];

    for (int half = 0; half < 2; ++half) {
        __syncthreads();
        for (int idx = tid; idx < 32 * 324; idx += 256) {
            int c  = idx / 324;
            int r2 = idx - c * 324;
            int ly = r2 / 18, lx = r2 - ly * 18;
            int gh = h0 + ly - 1, gw = w0 + lx - 1;
            float v = 0.f;
            if (gh >= 0 && gh < H_ && gw >= 0 && gw < W_)
                v = z[base_b + (((size_t)(half * 32 + c)) << 14) + gh * W_ + gw];
            zt[c][ly][lx] = v;
        }
        __syncthreads();
        for (int cl = 0; cl < 32; ++cl) {
            float zn[9];
#pragma unroll
            for (int i = 0; i < 3; ++i)
#pragma unroll
                for (int j = 0; j < 3; ++j)
                    zn[i * 3 + j] = zt[cl][ty + i][tx + j];
            int ci = half * 32 + cl;
            const float* wrow = w2 + (size_t)ci * 9;   // + o*576 + k
#pragma unroll
            for (int o = 0; o < C_; ++o) {
#pragma unroll
                for (int k = 0; k < 9; ++k)
                    acc[o] += wrow[(size_t)o * 576 + k] * zn[k];
            }
        }
    }
    int pix = h * W_ + w;
#pragma unroll
    for (int o = 0; o < C_; ++o)
        out[base_b + ((size_t)o << 14) + pix] = softplusf(acc[o]);
}

extern "C" void kernel_launch(void* const* d_in, const int* in_sizes, int n_in,
                              void* d_out, int out_size, void* d_ws, size_t ws_size,
                              hipStream_t stream)
{
    const float* x   = (const float*)d_in[0];
    const float* wr  = (const float*)d_in[1];
    const float* br  = (const float*)d_in[2];
    const float* gam = (const float*)d_in[3];
    const float* bet = (const float*)d_in[4];
    const float* wsp = (const float*)d_in[5];
    const float* bsp = (const float*)d_in[6];
    const float* w2  = (const float*)d_in[7];
    const float* b2  = (const float*)d_in[8];
    float* out = (float*)d_out;

    // workspace layout: z[8*64*128*128] f32, then stats sum[64]+sumsq[64], then ac[128]
    float* z     = (float*)d_ws;
    float* stats = (float*)((char*)d_ws + (size_t)NPIX * C_ * sizeof(float));
    float* ac    = stats + 128;

    // rbuf: reuse d_out as scratch for r (K4 overwrites it at the end)
    float* rbuf = out;

    hipMemsetAsync(stats, 0, 128 * sizeof(float), stream);
    k1_r_stats<<<NPIX / 256, 256, 0, stream>>>(x, wr, br, rbuf, stats);
    k2_finalize<<<1, 64, 0, stream>>>(stats, gam, bet, ac);
    k3_involution<<<NPIX / 256, 256, 0, stream>>>(x, rbuf, ac, wsp, bsp, z);
    k4_conv2<<<NPIX / 256, 256, 0, stream>>>(z, w2, b2, out);
}

// Round 2
// 191.503 us; speedup vs baseline: 4.0045x; 4.0045x over previous
//
#include <hip/hip_runtime.h>
#include <math.h>

#define H_ 128
#define W_ 128
#define C_ 64
#define B_ 8
#define HW 16384          // H_*W_
#define NPIX (B_*HW)      // 131072

typedef __attribute__((ext_vector_type(8))) short short8;
typedef __attribute__((ext_vector_type(4))) float f32x4;

__device__ __forceinline__ float softplusf(float v) {
    return fmaxf(v, 0.f) + log1pf(expf(-fabsf(v)));
}

__device__ __forceinline__ unsigned short f2bf(float f) {
    unsigned u = __builtin_bit_cast(unsigned, f);
    unsigned r = (u + 0x7fffu + ((u >> 16) & 1u)) >> 16;
    return (unsigned short)r;
}

// K0: transpose w2 [o][c][3][3] f32 -> bf16 MFMA A-fragments.
// wtr element index: ((wv*18 + f)*64 + lane)*8 + e, where f = koff*2 + ch,
// o = wv*16 + (lane&15), c = ch*32 + (lane>>4)*8 + e, value = w2[o*576 + c*9 + koff]
__global__ __launch_bounds__(256) void k0_wtr(const float* __restrict__ w2,
                                              unsigned short* __restrict__ wtr)
{
    int t = blockIdx.x * 256 + threadIdx.x;
    if (t >= 4 * 18 * 64) return;
    int lane = t & 63;
    int f    = (t >> 6) % 18;
    int wv   = t / (18 * 64);
    int koff = f >> 1, ch = f & 1;
    int o = wv * 16 + (lane & 15);
    int cb = ch * 32 + ((lane >> 4) << 3);
    uint4 pk;
    unsigned short* pv = (unsigned short*)&pk;
#pragma unroll
    for (int e = 0; e < 8; ++e)
        pv[e] = f2bf(w2[(size_t)o * 576 + (size_t)(cb + e) * 9 + koff]);
    *(uint4*)&wtr[(size_t)t * 8] = pk;
}

// K1: r = W_reduce @ x + b_reduce per pixel; write r (f32, channel-major, into
// d_out used as scratch); accumulate per-channel sum/sumsq for BN stats.
__global__ __launch_bounds__(256) void k1_r_stats(
    const float* __restrict__ x, const float* __restrict__ wr,
    const float* __restrict__ br, float* __restrict__ rbuf,
    float* __restrict__ stats)
{
    __shared__ float wrs[C_ * C_];
    __shared__ float lsum[C_], lsq[C_];
    int tid = threadIdx.x;
    for (int i = tid; i < C_ * C_; i += 256) wrs[i] = wr[i];
    if (tid < C_) { lsum[tid] = 0.f; lsq[tid] = 0.f; }
    __syncthreads();

    int pid = blockIdx.x * 256 + tid;
    int b   = pid >> 14;
    int rem = pid & (HW - 1);
    const float* xp = x + (((size_t)b * C_) << 14) + rem;

    float xv[C_];
#pragma unroll
    for (int c = 0; c < C_; ++c) xv[c] = xp[(size_t)c << 14];

    float* rp = rbuf + (((size_t)b * C_) << 14) + rem;
    int lane = tid & 63;

    for (int o = 0; o < C_; ++o) {
        float acc = br[o];
        const float4* wro = reinterpret_cast<const float4*>(&wrs[o * C_]);
#pragma unroll
        for (int c4 = 0; c4 < C_ / 4; ++c4) {
            float4 wv = wro[c4];
            acc += wv.x * xv[4*c4] + wv.y * xv[4*c4+1]
                 + wv.z * xv[4*c4+2] + wv.w * xv[4*c4+3];
        }
        rp[(size_t)o << 14] = acc;
        float s = acc, q = acc * acc;
#pragma unroll
        for (int m = 32; m; m >>= 1) {
            s += __shfl_xor(s, m, 64);
            q += __shfl_xor(q, m, 64);
        }
        if (lane == 0) { atomicAdd(&lsum[o], s); atomicAdd(&lsq[o], q); }
    }
    __syncthreads();
    if (tid < C_) {
        atomicAdd(&stats[tid], lsum[tid]);
        atomicAdd(&stats[C_ + tid], lsq[tid]);
    }
}

// K2: fold BN stats + gamma/beta into rn = relu(a*r + c)
__global__ void k2_finalize(const float* __restrict__ stats,
                            const float* __restrict__ gamma,
                            const float* __restrict__ beta,
                            float* __restrict__ ac)
{
    int o = threadIdx.x;
    if (o < C_) {
        float inv_n = 1.f / (float)NPIX;
        float mu  = stats[o] * inv_n;
        float var = stats[C_ + o] * inv_n - mu * mu;
        float is  = rsqrtf(var + 1e-5f);
        float a   = gamma[o] * is;
        ac[o]      = a;
        ac[C_ + o] = beta[o] - mu * a;
    }
}

// K3: kern[9] from r; involution over 3x3 x-patches; softplus ->
// z as bf16, PIXEL-MAJOR [b][h][w][c]
__global__ __launch_bounds__(256) void k3_involution(
    const float* __restrict__ x, const float* __restrict__ rbuf,
    const float* __restrict__ ac, const float* __restrict__ wspan,
    const float* __restrict__ bspan, unsigned short* __restrict__ zb)
{
    __shared__ float wst[C_ * 12];
    __shared__ float a_s[C_], c_s[C_];
    __shared__ float xt[4][18][19];
    int tid = threadIdx.x;
    for (int i = tid; i < 9 * C_; i += 256) {
        int k = i >> 6, o = i & 63;
        wst[o * 12 + k] = wspan[i];
    }
    if (tid < C_) { a_s[tid] = ac[tid]; c_s[tid] = ac[C_ + tid]; }

    int blk = blockIdx.x;
    int b = blk >> 6;
    int t = blk & 63;
    int h0 = (t >> 3) << 4;
    int w0 = (t & 7) << 4;
    int ty = tid >> 4, tx = tid & 15;
    int h = h0 + ty, w = w0 + tx;
    int pix = h * W_ + w;
    size_t base_b = ((size_t)b * C_) << 14;
    __syncthreads();

    float kern[9];
#pragma unroll
    for (int k = 0; k < 9; ++k) kern[k] = bspan[k];

    for (int o = 0; o < C_; ++o) {
        float rv = rbuf[base_b + ((size_t)o << 14) + pix];
        float rn = fmaxf(a_s[o] * rv + c_s[o], 0.f);
        const float* wo = &wst[o * 12];
#pragma unroll
        for (int k = 0; k < 9; ++k) kern[k] += wo[k] * rn;
    }

    // z pixel base (ushort units): ((b*16384 + pix) * 64)
    unsigned short* zp = zb + (((size_t)((b << 14) + pix)) << 6);

    for (int c0 = 0; c0 < C_; c0 += 4) {
        __syncthreads();
        for (int idx = tid; idx < 4 * 324; idx += 256) {
            int c  = idx / 324;
            int r2 = idx - c * 324;
            int ly = r2 / 18, lx = r2 - ly * 18;
            int gh = h0 + ly - 1, gw = w0 + lx - 1;
            float v = 0.f;
            if ((unsigned)gh < 128u && (unsigned)gw < 128u)
                v = x[base_b + ((size_t)(c0 + c) << 14) + (gh << 7) + gw];
            xt[c][ly][lx] = v;
        }
        __syncthreads();
        unsigned u01, u23;
        {
            float acc0 = 0.f, acc1 = 0.f, acc2 = 0.f, acc3 = 0.f;
#pragma unroll
            for (int i = 0; i < 3; ++i)
#pragma unroll
                for (int j = 0; j < 3; ++j) {
                    float kv = kern[i * 3 + j];
                    acc0 += kv * xt[0][ty + i][tx + j];
                    acc1 += kv * xt[1][ty + i][tx + j];
                    acc2 += kv * xt[2][ty + i][tx + j];
                    acc3 += kv * xt[3][ty + i][tx + j];
                }
            unsigned a0 = f2bf(softplusf(acc0)), a1 = f2bf(softplusf(acc1));
            unsigned a2 = f2bf(softplusf(acc2)), a3 = f2bf(softplusf(acc3));
            u01 = a0 | (a1 << 16);
            u23 = a2 | (a3 << 16);
        }
        uint2 pk; pk.x = u01; pk.y = u23;
        *(uint2*)&zp[c0] = pk;
    }
}

// K4: dense 3x3 conv 64->64 via implicit-GEMM MFMA (bf16 in, f32 acc)
// + bias + softplus. 4 waves; wave w owns out-channels [16w,16w+16).
__global__ __launch_bounds__(256) void k4_mfma(
    const unsigned short* __restrict__ zb, const unsigned short* __restrict__ wtr,
    const float* __restrict__ b2, float* __restrict__ out)
{
    // halo tile: 324 pixels x 64 ch bf16, chunk-swizzled: addr(ushort) =
    // p*64 + ((cg ^ (p&7))*8), cg = 16B chunk id (8 channels)
    __shared__ unsigned short zt[324 * 64];   // 41,472 B
    int tid = threadIdx.x;
    int blk = blockIdx.x;
    int b = blk >> 6;
    int t = blk & 63;
    int h0 = (t >> 3) << 4;
    int w0 = (t & 7) << 4;

    for (int idx = tid; idx < 324 * 8; idx += 256) {
        int p  = idx >> 3;
        int cg = idx & 7;
        int py = p / 18, px = p - py * 18;
        int gh = h0 + py - 1, gw = w0 + px - 1;
        uint4 v = make_uint4(0u, 0u, 0u, 0u);
        if ((unsigned)gh < 128u && (unsigned)gw < 128u)
            v = *(const uint4*)(zb + (((size_t)((b << 14) + (gh << 7) + gw)) << 6) + (cg << 3));
        *(uint4*)&zt[(p << 6) + ((cg ^ (p & 7)) << 3)] = v;
    }

    int wid  = tid >> 6, lane = tid & 63;
    int nl   = lane & 15;         // n (pixel col within row-tile)
    int kg   = lane >> 4;         // k-group

    short8 wf[18];
    const short8* wp = (const short8*)wtr;
#pragma unroll
    for (int f = 0; f < 18; ++f)
        wf[f] = wp[(size_t)(wid * 18 + f) * 64 + lane];

    f32x4 acc[16];
#pragma unroll
    for (int nt = 0; nt < 16; ++nt) acc[nt] = (f32x4){0.f, 0.f, 0.f, 0.f};

    __syncthreads();

#pragma unroll
    for (int y = 0; y < 18; ++y) {
        short8 bf[6];
#pragma unroll
        for (int j = 0; j < 3; ++j)
#pragma unroll
            for (int ch = 0; ch < 2; ++ch) {
                int p  = y * 18 + j + nl;
                int cg = ch * 4 + kg;
                bf[j * 2 + ch] = *(const short8*)&zt[(p << 6) + ((cg ^ (p & 7)) << 3)];
            }
#pragma unroll
        for (int i = 0; i < 3; ++i) {
            int nt = y - i;
            if (nt >= 0 && nt < 16) {
#pragma unroll
                for (int j = 0; j < 3; ++j)
#pragma unroll
                    for (int ch = 0; ch < 2; ++ch)
                        acc[nt] = __builtin_amdgcn_mfma_f32_16x16x32_bf16(
                            wf[(i * 3 + j) * 2 + ch], bf[j * 2 + ch], acc[nt], 0, 0, 0);
            }
        }
    }

    float bias[4];
#pragma unroll
    for (int r = 0; r < 4; ++r) bias[r] = b2[(wid << 4) + (kg << 2) + r];

    size_t ob = ((size_t)b) << 20;   // b * C * HW
#pragma unroll
    for (int nt = 0; nt < 16; ++nt) {
        int h = h0 + nt;
#pragma unroll
        for (int r = 0; r < 4; ++r) {
            int o = (wid << 4) + (kg << 2) + r;
            float v = acc[nt][r] + bias[r];
            out[ob + ((size_t)o << 14) + (h << 7) + w0 + nl] = softplusf(v);
        }
    }
}

extern "C" void kernel_launch(void* const* d_in, const int* in_sizes, int n_in,
                              void* d_out, int out_size, void* d_ws, size_t ws_size,
                              hipStream_t stream)
{
    const float* x   = (const float*)d_in[0];
    const float* wr  = (const float*)d_in[1];
    const float* br  = (const float*)d_in[2];
    const float* gam = (const float*)d_in[3];
    const float* bet = (const float*)d_in[4];
    const float* wsp = (const float*)d_in[5];
    const float* bsp = (const float*)d_in[6];
    const float* w2  = (const float*)d_in[7];
    const float* b2  = (const float*)d_in[8];
    float* out = (float*)d_out;

    // ws layout: zb bf16[NPIX*64] (16.78 MB) | wtr bf16[4608*8] | stats f32[128] | ac f32[128]
    unsigned short* zb  = (unsigned short*)d_ws;
    unsigned short* wtr = zb + (size_t)NPIX * C_;
    float* stats = (float*)(wtr + 4608 * 8);
    float* ac    = stats + 128;

    float* rbuf = out;   // d_out as f32 scratch for r (K4 overwrites at the end)

    hipMemsetAsync(stats, 0, 128 * sizeof(float), stream);
    k0_wtr<<<18, 256, 0, stream>>>(w2, wtr);
    k1_r_stats<<<NPIX / 256, 256, 0, stream>>>(x, wr, br, rbuf, stats);
    k2_finalize<<<1, 64, 0, stream>>>(stats, gam, bet, ac);
    k3_involution<<<NPIX / 256, 256, 0, stream>>>(x, rbuf, ac, wsp, bsp, zb);
    k4_mfma<<<NPIX / 256, 256, 0, stream>>>(zb, wtr, b2, out);
}